// Round 1
// baseline (2334.236 us; speedup 1.0000x reference)
//
#include <hip/hip_runtime.h>
#include <hip/hip_bf16.h>

#define D 64
#define NRAT 6

__device__ __forceinline__ float readlane_f(float v, int l) {
    int i = __builtin_amdgcn_readlane(__float_as_int(v), l);
    return __int_as_float(i);
}

// hu[n] = user_emb[user_ids[n]] + gender_emb[gender[n]];  hi analog.
__global__ void build_h(const int* __restrict__ uid, const int* __restrict__ iid,
                        const int* __restrict__ gender, const int* __restrict__ genres,
                        const float* __restrict__ user_emb, const float* __restrict__ item_emb,
                        const float* __restrict__ gender_emb, const float* __restrict__ genre_emb,
                        float* __restrict__ hu, float* __restrict__ hi, int NU, int NI) {
    int t = blockIdx.x * blockDim.x + threadIdx.x;
    int total = (NU + NI) * 16;            // one float4 per thread
    if (t >= total) return;
    int row = t >> 4, c = t & 15;
    if (row < NU) {
        int u = uid[row], g = gender[row];
        float4 a = ((const float4*)user_emb)[(size_t)u * 16 + c];
        float4 b = ((const float4*)gender_emb)[(size_t)g * 16 + c];
        ((float4*)hu)[(size_t)row * 16 + c] = make_float4(a.x+b.x, a.y+b.y, a.z+b.z, a.w+b.w);
    } else {
        int r2 = row - NU;
        int it = iid[r2], ge = genres[r2];
        float4 a = ((const float4*)item_emb)[(size_t)it * 16 + c];
        float4 b = ((const float4*)genre_emb)[(size_t)ge * 16 + c];
        ((float4*)hi)[(size_t)r2 * 16 + c] = make_float4(a.x+b.x, a.y+b.y, a.z+b.z, a.w+b.w);
    }
}

// One wave per edge: scatter raw source row into S[rating][dst][*] and bump degree.
__global__ void edge_scatter(const int* __restrict__ src_idx, const int* __restrict__ dst_idx,
                             const int* __restrict__ rating, const float* __restrict__ h_src,
                             float* __restrict__ S, float* __restrict__ cnt,
                             int E, int Ndst) {
    int lane = threadIdx.x & 63;
    int wave = (blockIdx.x * blockDim.x + threadIdx.x) >> 6;
    int nw   = (gridDim.x * blockDim.x) >> 6;
    for (int e = wave; e < E; e += nw) {
        int s = src_idx[e], dst = dst_idx[e], r = rating[e];
        float v = h_src[(size_t)s * D + lane];
        atomicAdd(&S[((size_t)r * Ndst + dst) * D + lane], v);
        if (lane == 0) atomicAdd(&cnt[dst], 1.0f);
    }
}

// Fused per-destination-node: hn = (1/max(cnt,1)) * sum_r Wr[r] @ S[r,n]
//   h2 = relu(Wlin[:, :64] @ h_dst[n] + Wlin[:, 64:] @ hn + blin)
//   out[n] = W2 @ h2 + b2
// Weights staged transposed in LDS ([j][d] layout, lane=d => conflict-free).
__global__ __launch_bounds__(512) void transform(
        const float* __restrict__ S, const float* __restrict__ cnt,
        const float* __restrict__ h_dst,
        const float* __restrict__ Wr,     // [6][64][64]
        const float* __restrict__ Wlin,   // [64][128]
        const float* __restrict__ blin,   // [64]
        const float* __restrict__ W2,     // [64][64]
        const float* __restrict__ b2,     // [64]
        float* __restrict__ out, int Ndst) {
    __shared__ float WrT[NRAT * D * D];   // [r][j][d] = Wr[r][d][j]
    __shared__ float WlT[2 * D * D];      // [j][d]    = Wlin[d][j], j<128
    __shared__ float W2T[D * D];          // [j][d]    = W2[d][j]

    for (int idx = threadIdx.x; idx < NRAT * D * D; idx += blockDim.x) {
        int r = idx >> 12, rem = idx & 4095, d = rem >> 6, j = rem & 63;
        WrT[(r << 12) + (j << 6) + d] = Wr[idx];
    }
    for (int idx = threadIdx.x; idx < 2 * D * D; idx += blockDim.x) {
        int d = idx >> 7, j = idx & 127;
        WlT[(j << 6) + d] = Wlin[idx];
    }
    for (int idx = threadIdx.x; idx < D * D; idx += blockDim.x) {
        int d = idx >> 6, j = idx & 63;
        W2T[(j << 6) + d] = W2[idx];
    }
    __syncthreads();

    int lane = threadIdx.x & 63;
    int wave = (blockIdx.x * blockDim.x + threadIdx.x) >> 6;
    int nw   = (gridDim.x * blockDim.x) >> 6;
    float bl = blin[lane], bb = b2[lane];

    for (int n = wave; n < Ndst; n += nw) {
        float inv = 1.0f / fmaxf(cnt[n], 1.0f);

        float a0 = 0.f, a1 = 0.f, a2 = 0.f, a3 = 0.f;
        #pragma unroll
        for (int r = 0; r < NRAT; ++r) {
            float s = S[((size_t)r * Ndst + n) * D + lane];
            const float* w = &WrT[r << 12];
            #pragma unroll
            for (int j = 0; j < D; j += 4) {
                a0 += w[((j + 0) << 6) + lane] * readlane_f(s, j + 0);
                a1 += w[((j + 1) << 6) + lane] * readlane_f(s, j + 1);
                a2 += w[((j + 2) << 6) + lane] * readlane_f(s, j + 2);
                a3 += w[((j + 3) << 6) + lane] * readlane_f(s, j + 3);
            }
        }
        float hn = (a0 + a1 + a2 + a3) * inv;

        float hd = h_dst[(size_t)n * D + lane];
        float c0 = bl, c1 = 0.f, c2 = 0.f, c3 = 0.f;
        #pragma unroll
        for (int j = 0; j < D; j += 4) {
            c0 += WlT[((j + 0) << 6) + lane] * readlane_f(hd, j + 0);
            c1 += WlT[((j + 1) << 6) + lane] * readlane_f(hd, j + 1);
            c2 += WlT[((j + 2) << 6) + lane] * readlane_f(hd, j + 2);
            c3 += WlT[((j + 3) << 6) + lane] * readlane_f(hd, j + 3);
        }
        #pragma unroll
        for (int j = 0; j < D; j += 4) {
            c0 += WlT[((64 + j + 0) << 6) + lane] * readlane_f(hn, j + 0);
            c1 += WlT[((64 + j + 1) << 6) + lane] * readlane_f(hn, j + 1);
            c2 += WlT[((64 + j + 2) << 6) + lane] * readlane_f(hn, j + 2);
            c3 += WlT[((64 + j + 3) << 6) + lane] * readlane_f(hn, j + 3);
        }
        float h2 = fmaxf(c0 + c1 + c2 + c3, 0.f);

        float o0 = bb, o1 = 0.f, o2 = 0.f, o3 = 0.f;
        #pragma unroll
        for (int j = 0; j < D; j += 4) {
            o0 += W2T[((j + 0) << 6) + lane] * readlane_f(h2, j + 0);
            o1 += W2T[((j + 1) << 6) + lane] * readlane_f(h2, j + 1);
            o2 += W2T[((j + 2) << 6) + lane] * readlane_f(h2, j + 2);
            o3 += W2T[((j + 3) << 6) + lane] * readlane_f(h2, j + 3);
        }
        out[(size_t)n * D + lane] = o0 + o1 + o2 + o3;
    }
}

extern "C" void kernel_launch(void* const* d_in, const int* in_sizes, int n_in,
                              void* d_out, int out_size, void* d_ws, size_t ws_size,
                              hipStream_t stream) {
    const int*   user_ids   = (const int*)  d_in[0];
    const int*   item_ids   = (const int*)  d_in[1];
    const int*   gender     = (const int*)  d_in[2];
    const int*   genres     = (const int*)  d_in[3];
    const int*   edge_user  = (const int*)  d_in[4];
    const int*   edge_item  = (const int*)  d_in[5];
    const int*   rating     = (const int*)  d_in[6];
    const float* user_emb   = (const float*)d_in[7];
    const float* item_emb   = (const float*)d_in[8];
    const float* gender_emb = (const float*)d_in[9];
    const float* genre_emb  = (const float*)d_in[10];
    const float* Wr_watched   = (const float*)d_in[11];
    const float* Wr_watchedby = (const float*)d_in[12];
    const float* Ww  = (const float*)d_in[13];
    const float* bw  = (const float*)d_in[14];
    const float* Wwb = (const float*)d_in[15];
    const float* bwb = (const float*)d_in[16];
    const float* Wf  = (const float*)d_in[17];
    const float* bf  = (const float*)d_in[18];
    const float* Vf  = (const float*)d_in[19];
    const float* bv  = (const float*)d_in[20];

    const int NU = in_sizes[0];
    const int NI = in_sizes[1];
    const int E  = in_sizes[4];

    float* out_f    = (float*)d_out;
    float* user_out = out_f;                       // [NU,64]
    float* item_out = out_f + (size_t)NU * D;      // [NI,64]

    // workspace layout (floats): [hu NU*64][hi NI*64][S 6*max(NU,NI)*64][cnt_u NU][cnt_i NI]
    float* ws = (float*)d_ws;
    float* hu = ws;
    float* hi = hu + (size_t)NU * D;
    float* S  = hi + (size_t)NI * D;
    size_t Smax = (size_t)NRAT * D * (size_t)((NU > NI) ? NU : NI);
    float* cnt_u = S + Smax;
    float* cnt_i = cnt_u + NU;

    // 1. node features
    int totalh = (NU + NI) * 16;
    build_h<<<(totalh + 255) / 256, 256, 0, stream>>>(
        user_ids, item_ids, gender, genres,
        user_emb, item_emb, gender_emb, genre_emb, hu, hi, NU, NI);

    // 2. direction 'watched' (users -> items), dst = items
    hipMemsetAsync(S, 0, (size_t)NRAT * NI * D * sizeof(float), stream);
    hipMemsetAsync(cnt_i, 0, (size_t)NI * sizeof(float), stream);
    edge_scatter<<<2048, 256, 0, stream>>>(edge_user, edge_item, rating, hu, S, cnt_i, E, NI);
    transform<<<256, 512, 0, stream>>>(S, cnt_i, hi, Wr_watched, Ww, bw, Vf, bv, item_out, NI);

    // 3. direction 'watchedby' (items -> users), dst = users
    hipMemsetAsync(S, 0, (size_t)NRAT * NU * D * sizeof(float), stream);
    hipMemsetAsync(cnt_u, 0, (size_t)NU * sizeof(float), stream);
    edge_scatter<<<2048, 256, 0, stream>>>(edge_item, edge_user, rating, hi, S, cnt_u, E, NU);
    transform<<<256, 512, 0, stream>>>(S, cnt_u, hu, Wr_watchedby, Wwb, bwb, Wf, bf, user_out, NU);
}

// Round 2
// 970.114 us; speedup vs baseline: 2.4061x; 2.4061x over previous
//
#include <hip/hip_runtime.h>
#include <hip/hip_bf16.h>

#define D 64
#define NRAT 6

typedef float f32x4 __attribute__((ext_vector_type(4)));
typedef short bf16x8 __attribute__((ext_vector_type(8)));

union FragU { uint32_t u[4]; bf16x8 v; };

__device__ __forceinline__ short f2bf(float f) {
    __hip_bfloat16 h = __float2bfloat16(f);
    union { __hip_bfloat16 h; short s; } c; c.h = h; return c.s;
}
__device__ __forceinline__ uint32_t pk2(float a, float b) {
    union { short s[2]; uint32_t u; } c; c.s[0] = f2bf(a); c.s[1] = f2bf(b); return c.u;
}

// hu[n] = user_emb[user_ids[n]] + gender_emb[gender[n]];  hi analog.
__global__ void build_h(const int* __restrict__ uid, const int* __restrict__ iid,
                        const int* __restrict__ gender, const int* __restrict__ genres,
                        const float* __restrict__ user_emb, const float* __restrict__ item_emb,
                        const float* __restrict__ gender_emb, const float* __restrict__ genre_emb,
                        float* __restrict__ hu, float* __restrict__ hi, int NU, int NI) {
    int t = blockIdx.x * blockDim.x + threadIdx.x;
    int total = (NU + NI) * 16;            // one float4 per thread
    if (t >= total) return;
    int row = t >> 4, c = t & 15;
    if (row < NU) {
        int u = uid[row], g = gender[row];
        float4 a = ((const float4*)user_emb)[(size_t)u * 16 + c];
        float4 b = ((const float4*)gender_emb)[(size_t)g * 16 + c];
        ((float4*)hu)[(size_t)row * 16 + c] = make_float4(a.x+b.x, a.y+b.y, a.z+b.z, a.w+b.w);
    } else {
        int r2 = row - NU;
        int it = iid[r2], ge = genres[r2];
        float4 a = ((const float4*)item_emb)[(size_t)it * 16 + c];
        float4 b = ((const float4*)genre_emb)[(size_t)ge * 16 + c];
        ((float4*)hi)[(size_t)r2 * 16 + c] = make_float4(a.x+b.x, a.y+b.y, a.z+b.z, a.w+b.w);
    }
}

// One wave per edge: scatter raw source row into S[rating][dst][*] and bump degree.
__global__ void edge_scatter(const int* __restrict__ src_idx, const int* __restrict__ dst_idx,
                             const int* __restrict__ rating, const float* __restrict__ h_src,
                             float* __restrict__ S, float* __restrict__ cnt,
                             int E, int Ndst) {
    int lane = threadIdx.x & 63;
    int wave = (blockIdx.x * blockDim.x + threadIdx.x) >> 6;
    int nw   = (gridDim.x * blockDim.x) >> 6;
    for (int e = wave; e < E; e += nw) {
        int s = src_idx[e], dst = dst_idx[e], r = rating[e];
        float v = h_src[(size_t)s * D + lane];
        atomicAdd(&S[((size_t)r * Ndst + dst) * D + lane], v);
        if (lane == 0) atomicAdd(&cnt[dst], 1.0f);
    }
}

// One-time: pack weights (bf16) into MFMA fragment order.
// pack[t16][tk][lane][e] = W[sub*64 + t16*16 + (lane&15)][tk*32 + (lane>>4)*8 + e]
__global__ void prep_weights(const float* __restrict__ Wr_w, const float* __restrict__ Wr_wb,
                             const float* __restrict__ Ww, const float* __restrict__ Wwb,
                             const float* __restrict__ Vf, const float* __restrict__ Wf,
                             short* __restrict__ pWrW, short* __restrict__ pWrWB,
                             short* __restrict__ pWw, short* __restrict__ pWwb,
                             short* __restrict__ pVf, short* __restrict__ pWf) {
    int t = blockIdx.x * blockDim.x + threadIdx.x;
    const float* src; short* dst; int K; int idx;
    if      (t < 24576) { src = Wr_w;  dst = pWrW;  K = 64;  idx = t; }
    else if (t < 49152) { src = Wr_wb; dst = pWrWB; K = 64;  idx = t - 24576; }
    else if (t < 57344) { src = Ww;    dst = pWw;   K = 128; idx = t - 49152; }
    else if (t < 65536) { src = Wwb;   dst = pWwb;  K = 128; idx = t - 57344; }
    else if (t < 69632) { src = Vf;    dst = pVf;   K = 64;  idx = t - 65536; }
    else if (t < 73728) { src = Wf;    dst = pWf;   K = 64;  idx = t - 69632; }
    else return;
    int per  = 64 * K;
    int sub  = idx / per;            // r for Wr packs, 0 otherwise
    int li   = idx % per;
    int e    = li & 7;
    int lane = (li >> 3) & 63;
    int frag = li >> 9;              // t16*(K/32) + tk
    int nkt  = K >> 5;
    int t16  = frag / nkt, tk = frag % nkt;
    int row  = t16 * 16 + (lane & 15);
    int col  = tk * 32 + (lane >> 4) * 8 + e;
    dst[idx] = f2bf(src[((size_t)(sub * 64 + row)) * K + col]);
}

// Fused per-16-node-tile MFMA transform (one wave per tile):
//   GEMM1 (transposed): hn^T = sum_r Wr[r] @ S[r,tile]^T, scaled by 1/cnt
//   GEMM2 (transposed): h2^T = relu(Wlin @ [hd|hn]^T + blin)
//   GEMM3 (normal):     out  = h2 @ W2^T + b2
// C-layout (col=lane&15=node) -> next B/A-frag via cvt_pk + shfl (no LDS).
__global__ __launch_bounds__(256) void transform_mfma(
        const float* __restrict__ S, const float* __restrict__ cnt,
        const float* __restrict__ hd,
        const short* __restrict__ pWr,    // [6][4][2][512]
        const short* __restrict__ pWlin,  // [4][4][512]
        const float* __restrict__ blin,
        const short* __restrict__ pW2,    // [4][2][512]
        const float* __restrict__ b2,
        float* __restrict__ out, int N) {
    const int lane = threadIdx.x & 63;
    const int m = lane & 15, q = lane >> 4;
    const int wave = (blockIdx.x * blockDim.x + threadIdx.x) >> 6;
    const int n0 = wave * 16;
    if (n0 >= N) return;
    int nrow = n0 + m; if (nrow > N - 1) nrow = N - 1;

    // ---- B1 frags from S (fp32 load + inline bf16 cvt): lane holds S[n0+m][kt*32+q*8+e]
    bf16x8 bS[NRAT][2];
    #pragma unroll
    for (int r = 0; r < NRAT; ++r) {
        const float* p = S + ((size_t)r * N + nrow) * D + q * 8;
        #pragma unroll
        for (int kt = 0; kt < 2; ++kt) {
            f32x4 lo = *(const f32x4*)(p + kt * 32);
            f32x4 hi = *(const f32x4*)(p + kt * 32 + 4);
            FragU f;
            f.u[0] = pk2(lo[0], lo[1]); f.u[1] = pk2(lo[2], lo[3]);
            f.u[2] = pk2(hi[0], hi[1]); f.u[3] = pk2(hi[2], hi[3]);
            bS[r][kt] = f.v;
        }
    }
    // ---- hd frags (cat dims 0..63)
    bf16x8 bH[2];
    {
        const float* p = hd + (size_t)nrow * D + q * 8;
        #pragma unroll
        for (int kt = 0; kt < 2; ++kt) {
            f32x4 lo = *(const f32x4*)(p + kt * 32);
            f32x4 hi = *(const f32x4*)(p + kt * 32 + 4);
            FragU f;
            f.u[0] = pk2(lo[0], lo[1]); f.u[1] = pk2(lo[2], lo[3]);
            f.u[2] = pk2(hi[0], hi[1]); f.u[3] = pk2(hi[2], hi[3]);
            bH[kt] = f.v;
        }
    }
    float inv = 1.0f / fmaxf(cnt[nrow], 1.0f);

    // ---- GEMM1: hn^T[i, n],  C1: col=m=node, row=it*16+q*4+reg = i
    f32x4 acc1[4] = {};
    #pragma unroll
    for (int it = 0; it < 4; ++it)
        #pragma unroll
        for (int r = 0; r < NRAT; ++r)
            #pragma unroll
            for (int kt = 0; kt < 2; ++kt) {
                bf16x8 a = *(const bf16x8*)(pWr + (((r * 4 + it) * 2 + kt) << 9) + (lane << 3));
                acc1[it] = __builtin_amdgcn_mfma_f32_16x16x32_bf16(a, bS[r][kt], acc1[it], 0, 0, 0);
            }
    #pragma unroll
    for (int it = 0; it < 4; ++it)
        #pragma unroll
        for (int rg = 0; rg < 4; ++rg) acc1[it][rg] *= inv;

    // ---- C1 -> B2 frags (hn part of cat): lane needs hn[n0+m][32w+8q+e]
    const int srcA = ((q & 1) << 5) + m;   // (2*(q&1))*16 + m
    const int srcB = srcA + 16;
    const bool hiq = (q >> 1) != 0;
    uint32_t u0[4], u1[4];
    #pragma unroll
    for (int it = 0; it < 4; ++it) {
        u0[it] = pk2(acc1[it][0], acc1[it][1]);
        u1[it] = pk2(acc1[it][2], acc1[it][3]);
    }
    bf16x8 bHN[2];
    #pragma unroll
    for (int w = 0; w < 2; ++w) {
        uint32_t aa0 = (uint32_t)__shfl((int)u0[2*w],   srcA), bb0 = (uint32_t)__shfl((int)u0[2*w+1], srcA);
        uint32_t aa1 = (uint32_t)__shfl((int)u1[2*w],   srcA), bb1 = (uint32_t)__shfl((int)u1[2*w+1], srcA);
        uint32_t aa2 = (uint32_t)__shfl((int)u0[2*w],   srcB), bb2 = (uint32_t)__shfl((int)u0[2*w+1], srcB);
        uint32_t aa3 = (uint32_t)__shfl((int)u1[2*w],   srcB), bb3 = (uint32_t)__shfl((int)u1[2*w+1], srcB);
        FragU f;
        f.u[0] = hiq ? bb0 : aa0;
        f.u[1] = hiq ? bb1 : aa1;
        f.u[2] = hiq ? bb2 : aa2;
        f.u[3] = hiq ? bb3 : aa3;
        bHN[w] = f.v;
    }

    // ---- GEMM2: h2^T[o, n]
    f32x4 acc2[4] = {};
    #pragma unroll
    for (int it = 0; it < 4; ++it)
        #pragma unroll
        for (int kt = 0; kt < 4; ++kt) {
            bf16x8 a = *(const bf16x8*)(pWlin + (((it * 4) + kt) << 9) + (lane << 3));
            bf16x8 b = (kt < 2) ? bH[kt] : bHN[kt - 2];
            acc2[it] = __builtin_amdgcn_mfma_f32_16x16x32_bf16(a, b, acc2[it], 0, 0, 0);
        }

    // ---- bias + relu, pack, -> A3 frags (h2 as A of GEMM3; same shuffle as B2 build)
    float vbl = blin[lane];
    #pragma unroll
    for (int it = 0; it < 4; ++it) {
        float h0 = fmaxf(acc2[it][0] + __shfl(vbl, it * 16 + q * 4 + 0), 0.f);
        float h1 = fmaxf(acc2[it][1] + __shfl(vbl, it * 16 + q * 4 + 1), 0.f);
        float h2 = fmaxf(acc2[it][2] + __shfl(vbl, it * 16 + q * 4 + 2), 0.f);
        float h3 = fmaxf(acc2[it][3] + __shfl(vbl, it * 16 + q * 4 + 3), 0.f);
        u0[it] = pk2(h0, h1);
        u1[it] = pk2(h2, h3);
    }
    bf16x8 bA3[2];
    #pragma unroll
    for (int w = 0; w < 2; ++w) {
        uint32_t aa0 = (uint32_t)__shfl((int)u0[2*w],   srcA), bb0 = (uint32_t)__shfl((int)u0[2*w+1], srcA);
        uint32_t aa1 = (uint32_t)__shfl((int)u1[2*w],   srcA), bb1 = (uint32_t)__shfl((int)u1[2*w+1], srcA);
        uint32_t aa2 = (uint32_t)__shfl((int)u0[2*w],   srcB), bb2 = (uint32_t)__shfl((int)u0[2*w+1], srcB);
        uint32_t aa3 = (uint32_t)__shfl((int)u1[2*w],   srcB), bb3 = (uint32_t)__shfl((int)u1[2*w+1], srcB);
        FragU f;
        f.u[0] = hiq ? bb0 : aa0;
        f.u[1] = hiq ? bb1 : aa1;
        f.u[2] = hiq ? bb2 : aa2;
        f.u[3] = hiq ? bb3 : aa3;
        bA3[w] = f.v;
    }

    // ---- GEMM3 (normal): C3[node_row, o],  row=q*4+reg=node, col=ct*16+m=o
    f32x4 acc3[4] = {};
    #pragma unroll
    for (int ct = 0; ct < 4; ++ct)
        #pragma unroll
        for (int kt = 0; kt < 2; ++kt) {
            bf16x8 b = *(const bf16x8*)(pW2 + (((ct * 2) + kt) << 9) + (lane << 3));
            acc3[ct] = __builtin_amdgcn_mfma_f32_16x16x32_bf16(bA3[kt], b, acc3[ct], 0, 0, 0);
        }
    #pragma unroll
    for (int ct = 0; ct < 4; ++ct) {
        float bb = b2[ct * 16 + m];
        #pragma unroll
        for (int rg = 0; rg < 4; ++rg) {
            int n = n0 + q * 4 + rg;
            if (n < N) out[(size_t)n * D + ct * 16 + m] = acc3[ct][rg] + bb;
        }
    }
}

extern "C" void kernel_launch(void* const* d_in, const int* in_sizes, int n_in,
                              void* d_out, int out_size, void* d_ws, size_t ws_size,
                              hipStream_t stream) {
    const int*   user_ids   = (const int*)  d_in[0];
    const int*   item_ids   = (const int*)  d_in[1];
    const int*   gender     = (const int*)  d_in[2];
    const int*   genres     = (const int*)  d_in[3];
    const int*   edge_user  = (const int*)  d_in[4];
    const int*   edge_item  = (const int*)  d_in[5];
    const int*   rating     = (const int*)  d_in[6];
    const float* user_emb   = (const float*)d_in[7];
    const float* item_emb   = (const float*)d_in[8];
    const float* gender_emb = (const float*)d_in[9];
    const float* genre_emb  = (const float*)d_in[10];
    const float* Wr_watched   = (const float*)d_in[11];
    const float* Wr_watchedby = (const float*)d_in[12];
    const float* Ww  = (const float*)d_in[13];
    const float* bw  = (const float*)d_in[14];
    const float* Wwb = (const float*)d_in[15];
    const float* bwb = (const float*)d_in[16];
    const float* Wf  = (const float*)d_in[17];
    const float* bf  = (const float*)d_in[18];
    const float* Vf  = (const float*)d_in[19];
    const float* bv  = (const float*)d_in[20];

    const int NU = in_sizes[0];
    const int NI = in_sizes[1];
    const int E  = in_sizes[4];
    const int maxN = (NU > NI) ? NU : NI;

    float* out_f    = (float*)d_out;
    float* user_out = out_f;                       // [NU,64]
    float* item_out = out_f + (size_t)NU * D;      // [NI,64]

    // ws layout (floats): hu, hi, S[6*maxN*64], cnt_u, cnt_i, then bf16 packs
    float* ws = (float*)d_ws;
    float* hu = ws;
    float* hi = hu + (size_t)NU * D;
    float* S  = hi + (size_t)NI * D;
    float* cnt_u = S + (size_t)NRAT * maxN * D;
    float* cnt_i = cnt_u + NU;
    size_t foff = (size_t)(cnt_i + NI - ws);
    foff = (foff + 7) & ~(size_t)7;                // 16B-align packs
    short* pWrW  = (short*)(ws + foff);
    short* pWrWB = pWrW  + 24576;
    short* pWw   = pWrWB + 24576;
    short* pWwb  = pWw   + 8192;
    short* pVf   = pWwb  + 8192;
    short* pWf   = pVf   + 4096;

    // 1. node features + weight packing
    int totalh = (NU + NI) * 16;
    build_h<<<(totalh + 255) / 256, 256, 0, stream>>>(
        user_ids, item_ids, gender, genres,
        user_emb, item_emb, gender_emb, genre_emb, hu, hi, NU, NI);
    prep_weights<<<288, 256, 0, stream>>>(Wr_watched, Wr_watchedby, Ww, Wwb, Vf, Wf,
                                          pWrW, pWrWB, pWw, pWwb, pVf, pWf);

    // 2. direction 'watched' (users -> items), dst = items
    hipMemsetAsync(S, 0, (size_t)NRAT * NI * D * sizeof(float), stream);
    hipMemsetAsync(cnt_i, 0, (size_t)NI * sizeof(float), stream);
    edge_scatter<<<2048, 256, 0, stream>>>(edge_user, edge_item, rating, hu, S, cnt_i, E, NI);
    {
        int tiles = (NI + 15) / 16, blocks = (tiles + 3) / 4;
        transform_mfma<<<blocks, 256, 0, stream>>>(S, cnt_i, hi, pWrW, pWw, bw, pVf, bv,
                                                   item_out, NI);
    }

    // 3. direction 'watchedby' (items -> users), dst = users
    hipMemsetAsync(S, 0, (size_t)NRAT * NU * D * sizeof(float), stream);
    hipMemsetAsync(cnt_u, 0, (size_t)NU * sizeof(float), stream);
    edge_scatter<<<2048, 256, 0, stream>>>(edge_item, edge_user, rating, hi, S, cnt_u, E, NU);
    {
        int tiles = (NU + 15) / 16, blocks = (tiles + 3) / 4;
        transform_mfma<<<blocks, 256, 0, stream>>>(S, cnt_u, hu, pWrWB, pWwb, bwb, pWf, bf,
                                                   user_out, NU);
    }
}

// Round 3
// 856.527 us; speedup vs baseline: 2.7252x; 1.1326x over previous
//
#include <hip/hip_runtime.h>
#include <hip/hip_bf16.h>

#define D 64
#define NRAT 6

typedef float f32x4 __attribute__((ext_vector_type(4)));
typedef short bf16x8 __attribute__((ext_vector_type(8)));

union FragU { uint32_t u[4]; bf16x8 v; };

__device__ __forceinline__ short f2bf(float f) {
    __hip_bfloat16 h = __float2bfloat16(f);
    union { __hip_bfloat16 h; short s; } c; c.h = h; return c.s;
}
__device__ __forceinline__ uint32_t pk2(float a, float b) {
    union { short s[2]; uint32_t u; } c; c.s[0] = f2bf(a); c.s[1] = f2bf(b); return c.u;
}

// hu[n] = user_emb[user_ids[n]] + gender_emb[gender[n]];  hi analog.
__global__ void build_h(const int* __restrict__ uid, const int* __restrict__ iid,
                        const int* __restrict__ gender, const int* __restrict__ genres,
                        const float* __restrict__ user_emb, const float* __restrict__ item_emb,
                        const float* __restrict__ gender_emb, const float* __restrict__ genre_emb,
                        float* __restrict__ hu, float* __restrict__ hi, int NU, int NI) {
    int t = blockIdx.x * blockDim.x + threadIdx.x;
    int total = (NU + NI) * 16;            // one float4 per thread
    if (t >= total) return;
    int row = t >> 4, c = t & 15;
    if (row < NU) {
        int u = uid[row], g = gender[row];
        float4 a = ((const float4*)user_emb)[(size_t)u * 16 + c];
        float4 b = ((const float4*)gender_emb)[(size_t)g * 16 + c];
        ((float4*)hu)[(size_t)row * 16 + c] = make_float4(a.x+b.x, a.y+b.y, a.z+b.z, a.w+b.w);
    } else {
        int r2 = row - NU;
        int it = iid[r2], ge = genres[r2];
        float4 a = ((const float4*)item_emb)[(size_t)it * 16 + c];
        float4 b = ((const float4*)genre_emb)[(size_t)ge * 16 + c];
        ((float4*)hi)[(size_t)r2 * 16 + c] = make_float4(a.x+b.x, a.y+b.y, a.z+b.z, a.w+b.w);
    }
}

// Per-edge histogram of both endpoints (int atomics on small L2-resident arrays).
__global__ void hist2(const int* __restrict__ eu, const int* __restrict__ ei,
                      int* __restrict__ cu, int* __restrict__ ci, int E) {
    int t = blockIdx.x * blockDim.x + threadIdx.x;
    if (t >= E) return;
    atomicAdd(&cu[eu[t]], 1);
    atomicAdd(&ci[ei[t]], 1);
}

// Single-block exclusive scan: off[0..N] (off[N]=total) and a cursor copy.
__global__ __launch_bounds__(1024) void scan_offsets(const int* __restrict__ cnt,
                                                     int* __restrict__ off,
                                                     int* __restrict__ cursor, int N) {
    __shared__ int sdata[1024];
    __shared__ int carry_s;
    const int t = threadIdx.x;
    if (t == 0) carry_s = 0;
    __syncthreads();
    const int PT = 16, CH = 1024 * PT;
    for (int base = 0; base < N; base += CH) {
        int carry = carry_s;
        int i0 = base + t * PT;
        int loc[PT]; int s = 0;
        #pragma unroll
        for (int k = 0; k < PT; ++k) {
            int idx = i0 + k;
            int v = (idx < N) ? cnt[idx] : 0;
            loc[k] = s; s += v;
        }
        sdata[t] = s; __syncthreads();
        for (int d = 1; d < 1024; d <<= 1) {
            int v = (t >= d) ? sdata[t - d] : 0; __syncthreads();
            sdata[t] += v; __syncthreads();
        }
        int total = sdata[1023];
        int excl = carry + (t ? sdata[t - 1] : 0);
        #pragma unroll
        for (int k = 0; k < PT; ++k) {
            int idx = i0 + k;
            if (idx < N) { int o = excl + loc[k]; off[idx] = o; cursor[idx] = o; }
        }
        __syncthreads();
        if (t == 0) carry_s = carry + total;
        __syncthreads();
    }
    if (t == 0) off[N] = carry_s;
}

// Bucket edges by dst: packed[pos] = src | (rating << 27).
__global__ void scatter_edges(const int* __restrict__ src, const int* __restrict__ dst,
                              const int* __restrict__ rating, int* __restrict__ cursor,
                              unsigned* __restrict__ packed, int E) {
    int t = blockIdx.x * blockDim.x + threadIdx.x;
    if (t >= E) return;
    int d = dst[t];
    int p = atomicAdd(&cursor[d], 1);
    packed[p] = (unsigned)src[t] | ((unsigned)rating[t] << 27);
}

// One wave per dst node (lane = dim): batch-load 64 edge metas coalesced,
// broadcast via readlane, gather 256B h_src rows, accumulate 6 rating sums
// in registers, store S rows exactly once (no atomics, no memset needed).
__global__ __launch_bounds__(256) void gather_reduce(
        const int* __restrict__ off, const unsigned* __restrict__ packed,
        const float* __restrict__ h_src, float* __restrict__ S, int Ndst) {
    int lane = threadIdx.x & 63;
    int n = (blockIdx.x * blockDim.x + threadIdx.x) >> 6;
    if (n >= Ndst) return;
    int b = off[n], e = off[n + 1];
    float a0 = 0.f, a1 = 0.f, a2 = 0.f, a3 = 0.f, a4 = 0.f, a5 = 0.f;
    for (int base = b; base < e; base += 64) {
        int idx = base + lane; if (idx > e - 1) idx = e - 1;
        unsigned meta = packed[idx];
        int cnt = e - base; if (cnt > 64) cnt = 64;
        for (int j = 0; j < cnt; ++j) {
            unsigned mm = (unsigned)__builtin_amdgcn_readlane((int)meta, j);
            int src = (int)(mm & 0x07FFFFFFu);
            int r   = (int)(mm >> 27);
            float v = h_src[(size_t)src * D + lane];
            a0 += (r == 0) ? v : 0.f;
            a1 += (r == 1) ? v : 0.f;
            a2 += (r == 2) ? v : 0.f;
            a3 += (r == 3) ? v : 0.f;
            a4 += (r == 4) ? v : 0.f;
            a5 += (r == 5) ? v : 0.f;
        }
    }
    size_t s0 = (size_t)n * D + lane;
    size_t st = (size_t)Ndst * D;
    S[s0]          = a0; S[s0 +     st] = a1; S[s0 + 2 * st] = a2;
    S[s0 + 3 * st] = a3; S[s0 + 4 * st] = a4; S[s0 + 5 * st] = a5;
}

// One-time: pack weights (bf16) into MFMA fragment order.
// pack[t16][tk][lane][e] = W[sub*64 + t16*16 + (lane&15)][tk*32 + (lane>>4)*8 + e]
__global__ void prep_weights(const float* __restrict__ Wr_w, const float* __restrict__ Wr_wb,
                             const float* __restrict__ Ww, const float* __restrict__ Wwb,
                             const float* __restrict__ Vf, const float* __restrict__ Wf,
                             short* __restrict__ pWrW, short* __restrict__ pWrWB,
                             short* __restrict__ pWw, short* __restrict__ pWwb,
                             short* __restrict__ pVf, short* __restrict__ pWf) {
    int t = blockIdx.x * blockDim.x + threadIdx.x;
    const float* src; short* dst; int K; int idx;
    if      (t < 24576) { src = Wr_w;  dst = pWrW;  K = 64;  idx = t; }
    else if (t < 49152) { src = Wr_wb; dst = pWrWB; K = 64;  idx = t - 24576; }
    else if (t < 57344) { src = Ww;    dst = pWw;   K = 128; idx = t - 49152; }
    else if (t < 65536) { src = Wwb;   dst = pWwb;  K = 128; idx = t - 57344; }
    else if (t < 69632) { src = Vf;    dst = pVf;   K = 64;  idx = t - 65536; }
    else if (t < 73728) { src = Wf;    dst = pWf;   K = 64;  idx = t - 69632; }
    else return;
    int per  = 64 * K;
    int sub  = idx / per;            // r for Wr packs, 0 otherwise
    int li   = idx % per;
    int e    = li & 7;
    int lane = (li >> 3) & 63;
    int frag = li >> 9;              // t16*(K/32) + tk
    int nkt  = K >> 5;
    int t16  = frag / nkt, tk = frag % nkt;
    int row  = t16 * 16 + (lane & 15);
    int col  = tk * 32 + (lane >> 4) * 8 + e;
    dst[idx] = f2bf(src[((size_t)(sub * 64 + row)) * K + col]);
}

// Fused per-16-node-tile MFMA transform (one wave per tile):
//   GEMM1 (transposed): hn^T = sum_r Wr[r] @ S[r,tile]^T, scaled by 1/deg
//   GEMM2 (transposed): h2^T = relu(Wlin @ [hd|hn]^T + blin)
//   GEMM3 (normal):     out  = h2 @ W2^T + b2
__global__ __launch_bounds__(256) void transform_mfma(
        const float* __restrict__ S, const int* __restrict__ off,
        const float* __restrict__ hd,
        const short* __restrict__ pWr,    // [6][4][2][512]
        const short* __restrict__ pWlin,  // [4][4][512]
        const float* __restrict__ blin,
        const short* __restrict__ pW2,    // [4][2][512]
        const float* __restrict__ b2,
        float* __restrict__ out, int N) {
    const int lane = threadIdx.x & 63;
    const int m = lane & 15, q = lane >> 4;
    const int wave = (blockIdx.x * blockDim.x + threadIdx.x) >> 6;
    const int n0 = wave * 16;
    if (n0 >= N) return;
    int nrow = n0 + m; if (nrow > N - 1) nrow = N - 1;

    // ---- B1 frags from S: lane holds S[r][n0+m][kt*32+q*8+e]
    bf16x8 bS[NRAT][2];
    #pragma unroll
    for (int r = 0; r < NRAT; ++r) {
        const float* p = S + ((size_t)r * N + nrow) * D + q * 8;
        #pragma unroll
        for (int kt = 0; kt < 2; ++kt) {
            f32x4 lo = *(const f32x4*)(p + kt * 32);
            f32x4 hi = *(const f32x4*)(p + kt * 32 + 4);
            FragU f;
            f.u[0] = pk2(lo[0], lo[1]); f.u[1] = pk2(lo[2], lo[3]);
            f.u[2] = pk2(hi[0], hi[1]); f.u[3] = pk2(hi[2], hi[3]);
            bS[r][kt] = f.v;
        }
    }
    // ---- hd frags (cat dims 0..63)
    bf16x8 bH[2];
    {
        const float* p = hd + (size_t)nrow * D + q * 8;
        #pragma unroll
        for (int kt = 0; kt < 2; ++kt) {
            f32x4 lo = *(const f32x4*)(p + kt * 32);
            f32x4 hi = *(const f32x4*)(p + kt * 32 + 4);
            FragU f;
            f.u[0] = pk2(lo[0], lo[1]); f.u[1] = pk2(lo[2], lo[3]);
            f.u[2] = pk2(hi[0], hi[1]); f.u[3] = pk2(hi[2], hi[3]);
            bH[kt] = f.v;
        }
    }
    int deg = off[nrow + 1] - off[nrow];
    float inv = 1.0f / fmaxf((float)deg, 1.0f);

    // ---- GEMM1: hn^T[i, n],  C1: col=m=node, row=it*16+q*4+reg = i
    f32x4 acc1[4] = {};
    #pragma unroll
    for (int it = 0; it < 4; ++it)
        #pragma unroll
        for (int r = 0; r < NRAT; ++r)
            #pragma unroll
            for (int kt = 0; kt < 2; ++kt) {
                bf16x8 a = *(const bf16x8*)(pWr + (((r * 4 + it) * 2 + kt) << 9) + (lane << 3));
                acc1[it] = __builtin_amdgcn_mfma_f32_16x16x32_bf16(a, bS[r][kt], acc1[it], 0, 0, 0);
            }
    #pragma unroll
    for (int it = 0; it < 4; ++it)
        #pragma unroll
        for (int rg = 0; rg < 4; ++rg) acc1[it][rg] *= inv;

    // ---- C1 -> B2 frags (hn part of cat): lane needs hn[n0+m][32w+8q+e]
    const int srcA = ((q & 1) << 5) + m;
    const int srcB = srcA + 16;
    const bool hiq = (q >> 1) != 0;
    uint32_t u0[4], u1[4];
    #pragma unroll
    for (int it = 0; it < 4; ++it) {
        u0[it] = pk2(acc1[it][0], acc1[it][1]);
        u1[it] = pk2(acc1[it][2], acc1[it][3]);
    }
    bf16x8 bHN[2];
    #pragma unroll
    for (int w = 0; w < 2; ++w) {
        uint32_t aa0 = (uint32_t)__shfl((int)u0[2*w],   srcA), bb0 = (uint32_t)__shfl((int)u0[2*w+1], srcA);
        uint32_t aa1 = (uint32_t)__shfl((int)u1[2*w],   srcA), bb1 = (uint32_t)__shfl((int)u1[2*w+1], srcA);
        uint32_t aa2 = (uint32_t)__shfl((int)u0[2*w],   srcB), bb2 = (uint32_t)__shfl((int)u0[2*w+1], srcB);
        uint32_t aa3 = (uint32_t)__shfl((int)u1[2*w],   srcB), bb3 = (uint32_t)__shfl((int)u1[2*w+1], srcB);
        FragU f;
        f.u[0] = hiq ? bb0 : aa0;
        f.u[1] = hiq ? bb1 : aa1;
        f.u[2] = hiq ? bb2 : aa2;
        f.u[3] = hiq ? bb3 : aa3;
        bHN[w] = f.v;
    }

    // ---- GEMM2: h2^T[o, n]
    f32x4 acc2[4] = {};
    #pragma unroll
    for (int it = 0; it < 4; ++it)
        #pragma unroll
        for (int kt = 0; kt < 4; ++kt) {
            bf16x8 a = *(const bf16x8*)(pWlin + (((it * 4) + kt) << 9) + (lane << 3));
            bf16x8 b = (kt < 2) ? bH[kt] : bHN[kt - 2];
            acc2[it] = __builtin_amdgcn_mfma_f32_16x16x32_bf16(a, b, acc2[it], 0, 0, 0);
        }

    // ---- bias + relu, pack, -> A3 frags
    float vbl = blin[lane];
    #pragma unroll
    for (int it = 0; it < 4; ++it) {
        float h0 = fmaxf(acc2[it][0] + __shfl(vbl, it * 16 + q * 4 + 0), 0.f);
        float h1 = fmaxf(acc2[it][1] + __shfl(vbl, it * 16 + q * 4 + 1), 0.f);
        float h2 = fmaxf(acc2[it][2] + __shfl(vbl, it * 16 + q * 4 + 2), 0.f);
        float h3 = fmaxf(acc2[it][3] + __shfl(vbl, it * 16 + q * 4 + 3), 0.f);
        u0[it] = pk2(h0, h1);
        u1[it] = pk2(h2, h3);
    }
    bf16x8 bA3[2];
    #pragma unroll
    for (int w = 0; w < 2; ++w) {
        uint32_t aa0 = (uint32_t)__shfl((int)u0[2*w],   srcA), bb0 = (uint32_t)__shfl((int)u0[2*w+1], srcA);
        uint32_t aa1 = (uint32_t)__shfl((int)u1[2*w],   srcA), bb1 = (uint32_t)__shfl((int)u1[2*w+1], srcA);
        uint32_t aa2 = (uint32_t)__shfl((int)u0[2*w],   srcB), bb2 = (uint32_t)__shfl((int)u0[2*w+1], srcB);
        uint32_t aa3 = (uint32_t)__shfl((int)u1[2*w],   srcB), bb3 = (uint32_t)__shfl((int)u1[2*w+1], srcB);
        FragU f;
        f.u[0] = hiq ? bb0 : aa0;
        f.u[1] = hiq ? bb1 : aa1;
        f.u[2] = hiq ? bb2 : aa2;
        f.u[3] = hiq ? bb3 : aa3;
        bA3[w] = f.v;
    }

    // ---- GEMM3 (normal): C3[node_row, o],  row=q*4+reg=node, col=ct*16+m=o
    f32x4 acc3[4] = {};
    #pragma unroll
    for (int ct = 0; ct < 4; ++ct)
        #pragma unroll
        for (int kt = 0; kt < 2; ++kt) {
            bf16x8 b = *(const bf16x8*)(pW2 + (((ct * 2) + kt) << 9) + (lane << 3));
            acc3[ct] = __builtin_amdgcn_mfma_f32_16x16x32_bf16(bA3[kt], b, acc3[ct], 0, 0, 0);
        }
    #pragma unroll
    for (int ct = 0; ct < 4; ++ct) {
        float bb = b2[ct * 16 + m];
        #pragma unroll
        for (int rg = 0; rg < 4; ++rg) {
            int n = n0 + q * 4 + rg;
            if (n < N) out[(size_t)n * D + ct * 16 + m] = acc3[ct][rg] + bb;
        }
    }
}

extern "C" void kernel_launch(void* const* d_in, const int* in_sizes, int n_in,
                              void* d_out, int out_size, void* d_ws, size_t ws_size,
                              hipStream_t stream) {
    const int*   user_ids   = (const int*)  d_in[0];
    const int*   item_ids   = (const int*)  d_in[1];
    const int*   gender     = (const int*)  d_in[2];
    const int*   genres     = (const int*)  d_in[3];
    const int*   edge_user  = (const int*)  d_in[4];
    const int*   edge_item  = (const int*)  d_in[5];
    const int*   rating     = (const int*)  d_in[6];
    const float* user_emb   = (const float*)d_in[7];
    const float* item_emb   = (const float*)d_in[8];
    const float* gender_emb = (const float*)d_in[9];
    const float* genre_emb  = (const float*)d_in[10];
    const float* Wr_watched   = (const float*)d_in[11];
    const float* Wr_watchedby = (const float*)d_in[12];
    const float* Ww  = (const float*)d_in[13];
    const float* bw  = (const float*)d_in[14];
    const float* Wwb = (const float*)d_in[15];
    const float* bwb = (const float*)d_in[16];
    const float* Wf  = (const float*)d_in[17];
    const float* bf  = (const float*)d_in[18];
    const float* Vf  = (const float*)d_in[19];
    const float* bv  = (const float*)d_in[20];

    const int NU = in_sizes[0];
    const int NI = in_sizes[1];
    const int E  = in_sizes[4];
    const int maxN = (NU > NI) ? NU : NI;

    float* out_f    = (float*)d_out;
    float* user_out = out_f;                       // [NU,64]
    float* item_out = out_f + (size_t)NU * D;      // [NI,64]

    // ws layout: hu, hi, S[6*maxN*64] (floats), bf16 packs, then int metadata
    float* ws = (float*)d_ws;
    float* hu = ws;
    float* hi = hu + (size_t)NU * D;
    float* S  = hi + (size_t)NI * D;
    size_t foff = (size_t)(S + (size_t)NRAT * maxN * D - ws);
    foff = (foff + 7) & ~(size_t)7;                // 16B-align packs
    short* pWrW  = (short*)(ws + foff);
    short* pWrWB = pWrW  + 24576;
    short* pWw   = pWrWB + 24576;
    short* pWwb  = pWw   + 8192;
    short* pVf   = pWwb  + 8192;
    short* pWf   = pVf   + 4096;
    int* cntU   = (int*)(pWf + 4096);
    int* cntI   = cntU + NU;
    int* offU   = cntI + NI;            // NU+1
    int* offI   = offU + NU + 1;        // NI+1
    int* cursor = offI + NI + 1;        // maxN (shared serially by both directions)
    unsigned* packed = (unsigned*)(cursor + maxN);  // E (shared serially)

    // 1. node features + weight packing + histograms
    int totalh = (NU + NI) * 16;
    build_h<<<(totalh + 255) / 256, 256, 0, stream>>>(
        user_ids, item_ids, gender, genres,
        user_emb, item_emb, gender_emb, genre_emb, hu, hi, NU, NI);
    prep_weights<<<288, 256, 0, stream>>>(Wr_watched, Wr_watchedby, Ww, Wwb, Vf, Wf,
                                          pWrW, pWrWB, pWw, pWwb, pVf, pWf);
    hipMemsetAsync(cntU, 0, (size_t)(NU + NI) * sizeof(int), stream);
    hist2<<<(E + 255) / 256, 256, 0, stream>>>(edge_user, edge_item, cntU, cntI, E);

    // 2. direction 'watched' (users -> items), dst = items
    scan_offsets<<<1, 1024, 0, stream>>>(cntI, offI, cursor, NI);
    scatter_edges<<<(E + 255) / 256, 256, 0, stream>>>(edge_user, edge_item, rating,
                                                       cursor, packed, E);
    gather_reduce<<<(NI + 3) / 4, 256, 0, stream>>>(offI, packed, hu, S, NI);
    {
        int tiles = (NI + 15) / 16, blocks = (tiles + 3) / 4;
        transform_mfma<<<blocks, 256, 0, stream>>>(S, offI, hi, pWrW, pWw, bw, pVf, bv,
                                                   item_out, NI);
    }

    // 3. direction 'watchedby' (items -> users), dst = users
    scan_offsets<<<1, 1024, 0, stream>>>(cntU, offU, cursor, NU);
    scatter_edges<<<(E + 255) / 256, 256, 0, stream>>>(edge_item, edge_user, rating,
                                                       cursor, packed, E);
    gather_reduce<<<(NU + 3) / 4, 256, 0, stream>>>(offU, packed, hi, S, NU);
    {
        int tiles = (NU + 15) / 16, blocks = (tiles + 3) / 4;
        transform_mfma<<<blocks, 256, 0, stream>>>(S, offU, hu, pWrWB, pWwb, bwb, pWf, bf,
                                                   user_out, NU);
    }
}

// Round 4
// 690.324 us; speedup vs baseline: 3.3814x; 1.2408x over previous
//
#include <hip/hip_runtime.h>
#include <hip/hip_bf16.h>

#define D 64
#define NRAT 6
#define SCAN_CHUNK 4096   // 256 threads x 16 elements

typedef float f32x4 __attribute__((ext_vector_type(4)));
typedef short bf16x8 __attribute__((ext_vector_type(8)));

union FragU { uint32_t u[4]; bf16x8 v; };

__device__ __forceinline__ short f2bf(float f) {
    __hip_bfloat16 h = __float2bfloat16(f);
    union { __hip_bfloat16 h; short s; } c; c.h = h; return c.s;
}
__device__ __forceinline__ uint32_t pk2(float a, float b) {
    union { short s[2]; uint32_t u; } c; c.s[0] = f2bf(a); c.s[1] = f2bf(b); return c.u;
}

// hu[n] = user_emb[user_ids[n]] + gender_emb[gender[n]];  hi analog.
__global__ void build_h(const int* __restrict__ uid, const int* __restrict__ iid,
                        const int* __restrict__ gender, const int* __restrict__ genres,
                        const float* __restrict__ user_emb, const float* __restrict__ item_emb,
                        const float* __restrict__ gender_emb, const float* __restrict__ genre_emb,
                        float* __restrict__ hu, float* __restrict__ hi, int NU, int NI) {
    int t = blockIdx.x * blockDim.x + threadIdx.x;
    int total = (NU + NI) * 16;            // one float4 per thread
    if (t >= total) return;
    int row = t >> 4, c = t & 15;
    if (row < NU) {
        int u = uid[row], g = gender[row];
        float4 a = ((const float4*)user_emb)[(size_t)u * 16 + c];
        float4 b = ((const float4*)gender_emb)[(size_t)g * 16 + c];
        ((float4*)hu)[(size_t)row * 16 + c] = make_float4(a.x+b.x, a.y+b.y, a.z+b.z, a.w+b.w);
    } else {
        int r2 = row - NU;
        int it = iid[r2], ge = genres[r2];
        float4 a = ((const float4*)item_emb)[(size_t)it * 16 + c];
        float4 b = ((const float4*)genre_emb)[(size_t)ge * 16 + c];
        ((float4*)hi)[(size_t)r2 * 16 + c] = make_float4(a.x+b.x, a.y+b.y, a.z+b.z, a.w+b.w);
    }
}

// Per-edge histogram of both endpoints into cntAll = [items(NI) | users(NU)].
__global__ void hist2(const int* __restrict__ eu, const int* __restrict__ ei,
                      int* __restrict__ cntAll, int NI, int E) {
    int t = blockIdx.x * blockDim.x + threadIdx.x;
    if (t >= E) return;
    atomicAdd(&cntAll[ei[t]], 1);
    atomicAdd(&cntAll[NI + eu[t]], 1);
}

// Hierarchical scan, stage 1: per-block sums over the concatenated cnt array.
// Blocks [0,nbI) cover items, [nbI,nbTot) cover users (no block crosses segments).
__global__ __launch_bounds__(256) void scan_blocks(const int* __restrict__ cnt,
                                                   int NI, int NU, int nbI,
                                                   int* __restrict__ part) {
    int b = blockIdx.x, t = threadIdx.x;
    bool isU = (b >= nbI);
    int segBase = isU ? NI : 0;
    int segLen  = isU ? NU : NI;
    int rel     = isU ? b - nbI : b;
    int i0 = rel * SCAN_CHUNK + t * 16;
    int s = 0;
    #pragma unroll
    for (int k = 0; k < 16; ++k) { int idx = i0 + k; if (idx < segLen) s += cnt[segBase + idx]; }
    __shared__ int red[256];
    red[t] = s; __syncthreads();
    for (int d = 128; d > 0; d >>= 1) { if (t < d) red[t] += red[t + d]; __syncthreads(); }
    if (t == 0) part[b] = red[0];
}

// Stage 2: each block computes its base from the partials of its segment,
// scans its 4096-chunk, writes off[] and cursor[]. Segment totals == E.
__global__ __launch_bounds__(256) void scan_apply(const int* __restrict__ cnt,
                                                  int NI, int NU, int nbI,
                                                  const int* __restrict__ part,
                                                  int* __restrict__ offI, int* __restrict__ offU,
                                                  int* __restrict__ curI, int* __restrict__ curU,
                                                  int E) {
    int b = blockIdx.x, t = threadIdx.x;
    bool isU = (b >= nbI);
    int segBase = isU ? NI : 0;
    int segLen  = isU ? NU : NI;
    int rel     = isU ? b - nbI : b;
    int* off = isU ? offU : offI;
    int* cur = isU ? curU : curI;
    int segPart = isU ? nbI : 0;

    __shared__ int sdata[256];
    // base = sum of partials with lower rel index in this segment
    sdata[t] = (t < rel) ? part[segPart + t] : 0;
    __syncthreads();
    for (int d = 128; d > 0; d >>= 1) { if (t < d) sdata[t] += sdata[t + d]; __syncthreads(); }
    int base = sdata[0];
    __syncthreads();

    int i0 = rel * SCAN_CHUNK + t * 16;
    int loc[16]; int s = 0;
    #pragma unroll
    for (int k = 0; k < 16; ++k) {
        int idx = i0 + k;
        int c = (idx < segLen) ? cnt[segBase + idx] : 0;
        loc[k] = s; s += c;
    }
    sdata[t] = s; __syncthreads();
    for (int d = 1; d < 256; d <<= 1) {
        int v = (t >= d) ? sdata[t - d] : 0;
        __syncthreads();
        sdata[t] += v;
        __syncthreads();
    }
    int excl = base + (t ? sdata[t - 1] : 0);
    #pragma unroll
    for (int k = 0; k < 16; ++k) {
        int idx = i0 + k;
        if (idx < segLen) { int o = excl + loc[k]; off[idx] = o; cur[idx] = o; }
    }
    if (b == 0 && t == 0) { offI[NI] = E; offU[NU] = E; }
}

// Bucket edges by dst: packed[pos] = src | (rating << 27).
__global__ void scatter_edges(const int* __restrict__ src, const int* __restrict__ dst,
                              const int* __restrict__ rating, int* __restrict__ cursor,
                              unsigned* __restrict__ packed, int E) {
    int t = blockIdx.x * blockDim.x + threadIdx.x;
    if (t >= E) return;
    int d = dst[t];
    int p = atomicAdd(&cursor[d], 1);
    packed[p] = (unsigned)src[t] | ((unsigned)rating[t] << 27);
}

// One wave per dst node (lane = dim): batch-load 64 edge metas coalesced,
// broadcast via readlane, gather 256B h_src rows, accumulate 6 rating sums
// in registers, store S rows exactly once (no atomics, no memset needed).
__global__ __launch_bounds__(256) void gather_reduce(
        const int* __restrict__ off, const unsigned* __restrict__ packed,
        const float* __restrict__ h_src, float* __restrict__ S, int Ndst) {
    int lane = threadIdx.x & 63;
    int n = (blockIdx.x * blockDim.x + threadIdx.x) >> 6;
    if (n >= Ndst) return;
    int b = off[n], e = off[n + 1];
    float a0 = 0.f, a1 = 0.f, a2 = 0.f, a3 = 0.f, a4 = 0.f, a5 = 0.f;
    for (int base = b; base < e; base += 64) {
        int idx = base + lane; if (idx > e - 1) idx = e - 1;
        unsigned meta = packed[idx];
        int cnt = e - base; if (cnt > 64) cnt = 64;
        for (int j = 0; j < cnt; ++j) {
            unsigned mm = (unsigned)__builtin_amdgcn_readlane((int)meta, j);
            int src = (int)(mm & 0x07FFFFFFu);
            int r   = (int)(mm >> 27);
            float v = h_src[(size_t)src * D + lane];
            a0 += (r == 0) ? v : 0.f;
            a1 += (r == 1) ? v : 0.f;
            a2 += (r == 2) ? v : 0.f;
            a3 += (r == 3) ? v : 0.f;
            a4 += (r == 4) ? v : 0.f;
            a5 += (r == 5) ? v : 0.f;
        }
    }
    size_t s0 = (size_t)n * D + lane;
    size_t st = (size_t)Ndst * D;
    S[s0]          = a0; S[s0 +     st] = a1; S[s0 + 2 * st] = a2;
    S[s0 + 3 * st] = a3; S[s0 + 4 * st] = a4; S[s0 + 5 * st] = a5;
}

// One-time: pack weights (bf16) into MFMA fragment order.
// pack[t16][tk][lane][e] = W[sub*64 + t16*16 + (lane&15)][tk*32 + (lane>>4)*8 + e]
__global__ void prep_weights(const float* __restrict__ Wr_w, const float* __restrict__ Wr_wb,
                             const float* __restrict__ Ww, const float* __restrict__ Wwb,
                             const float* __restrict__ Vf, const float* __restrict__ Wf,
                             short* __restrict__ pWrW, short* __restrict__ pWrWB,
                             short* __restrict__ pWw, short* __restrict__ pWwb,
                             short* __restrict__ pVf, short* __restrict__ pWf) {
    int t = blockIdx.x * blockDim.x + threadIdx.x;
    const float* src; short* dst; int K; int idx;
    if      (t < 24576) { src = Wr_w;  dst = pWrW;  K = 64;  idx = t; }
    else if (t < 49152) { src = Wr_wb; dst = pWrWB; K = 64;  idx = t - 24576; }
    else if (t < 57344) { src = Ww;    dst = pWw;   K = 128; idx = t - 49152; }
    else if (t < 65536) { src = Wwb;   dst = pWwb;  K = 128; idx = t - 57344; }
    else if (t < 69632) { src = Vf;    dst = pVf;   K = 64;  idx = t - 65536; }
    else if (t < 73728) { src = Wf;    dst = pWf;   K = 64;  idx = t - 69632; }
    else return;
    int per  = 64 * K;
    int sub  = idx / per;            // r for Wr packs, 0 otherwise
    int li   = idx % per;
    int e    = li & 7;
    int lane = (li >> 3) & 63;
    int frag = li >> 9;              // t16*(K/32) + tk
    int nkt  = K >> 5;
    int t16  = frag / nkt, tk = frag % nkt;
    int row  = t16 * 16 + (lane & 15);
    int col  = tk * 32 + (lane >> 4) * 8 + e;
    dst[idx] = f2bf(src[((size_t)(sub * 64 + row)) * K + col]);
}

// Fused per-16-node-tile MFMA transform (one wave per tile):
//   GEMM1 (transposed): hn^T = sum_r Wr[r] @ S[r,tile]^T, scaled by 1/deg
//   GEMM2 (transposed): h2^T = relu(Wlin @ [hd|hn]^T + blin)
//   GEMM3 (normal):     out  = h2 @ W2^T + b2
__global__ __launch_bounds__(256) void transform_mfma(
        const float* __restrict__ S, const int* __restrict__ off,
        const float* __restrict__ hd,
        const short* __restrict__ pWr,    // [6][4][2][512]
        const short* __restrict__ pWlin,  // [4][4][512]
        const float* __restrict__ blin,
        const short* __restrict__ pW2,    // [4][2][512]
        const float* __restrict__ b2,
        float* __restrict__ out, int N) {
    const int lane = threadIdx.x & 63;
    const int m = lane & 15, q = lane >> 4;
    const int wave = (blockIdx.x * blockDim.x + threadIdx.x) >> 6;
    const int n0 = wave * 16;
    if (n0 >= N) return;
    int nrow = n0 + m; if (nrow > N - 1) nrow = N - 1;

    // ---- B1 frags from S: lane holds S[r][n0+m][kt*32+q*8+e]
    bf16x8 bS[NRAT][2];
    #pragma unroll
    for (int r = 0; r < NRAT; ++r) {
        const float* p = S + ((size_t)r * N + nrow) * D + q * 8;
        #pragma unroll
        for (int kt = 0; kt < 2; ++kt) {
            f32x4 lo = *(const f32x4*)(p + kt * 32);
            f32x4 hi = *(const f32x4*)(p + kt * 32 + 4);
            FragU f;
            f.u[0] = pk2(lo[0], lo[1]); f.u[1] = pk2(lo[2], lo[3]);
            f.u[2] = pk2(hi[0], hi[1]); f.u[3] = pk2(hi[2], hi[3]);
            bS[r][kt] = f.v;
        }
    }
    // ---- hd frags (cat dims 0..63)
    bf16x8 bH[2];
    {
        const float* p = hd + (size_t)nrow * D + q * 8;
        #pragma unroll
        for (int kt = 0; kt < 2; ++kt) {
            f32x4 lo = *(const f32x4*)(p + kt * 32);
            f32x4 hi = *(const f32x4*)(p + kt * 32 + 4);
            FragU f;
            f.u[0] = pk2(lo[0], lo[1]); f.u[1] = pk2(lo[2], lo[3]);
            f.u[2] = pk2(hi[0], hi[1]); f.u[3] = pk2(hi[2], hi[3]);
            bH[kt] = f.v;
        }
    }
    int deg = off[nrow + 1] - off[nrow];
    float inv = 1.0f / fmaxf((float)deg, 1.0f);

    // ---- GEMM1: hn^T[i, n],  C1: col=m=node, row=it*16+q*4+reg = i
    f32x4 acc1[4] = {};
    #pragma unroll
    for (int it = 0; it < 4; ++it)
        #pragma unroll
        for (int r = 0; r < NRAT; ++r)
            #pragma unroll
            for (int kt = 0; kt < 2; ++kt) {
                bf16x8 a = *(const bf16x8*)(pWr + (((r * 4 + it) * 2 + kt) << 9) + (lane << 3));
                acc1[it] = __builtin_amdgcn_mfma_f32_16x16x32_bf16(a, bS[r][kt], acc1[it], 0, 0, 0);
            }
    #pragma unroll
    for (int it = 0; it < 4; ++it)
        #pragma unroll
        for (int rg = 0; rg < 4; ++rg) acc1[it][rg] *= inv;

    // ---- C1 -> B2 frags (hn part of cat): lane needs hn[n0+m][32w+8q+e]
    const int srcA = ((q & 1) << 5) + m;
    const int srcB = srcA + 16;
    const bool hiq = (q >> 1) != 0;
    uint32_t u0[4], u1[4];
    #pragma unroll
    for (int it = 0; it < 4; ++it) {
        u0[it] = pk2(acc1[it][0], acc1[it][1]);
        u1[it] = pk2(acc1[it][2], acc1[it][3]);
    }
    bf16x8 bHN[2];
    #pragma unroll
    for (int w = 0; w < 2; ++w) {
        uint32_t aa0 = (uint32_t)__shfl((int)u0[2*w],   srcA), bb0 = (uint32_t)__shfl((int)u0[2*w+1], srcA);
        uint32_t aa1 = (uint32_t)__shfl((int)u1[2*w],   srcA), bb1 = (uint32_t)__shfl((int)u1[2*w+1], srcA);
        uint32_t aa2 = (uint32_t)__shfl((int)u0[2*w],   srcB), bb2 = (uint32_t)__shfl((int)u0[2*w+1], srcB);
        uint32_t aa3 = (uint32_t)__shfl((int)u1[2*w],   srcB), bb3 = (uint32_t)__shfl((int)u1[2*w+1], srcB);
        FragU f;
        f.u[0] = hiq ? bb0 : aa0;
        f.u[1] = hiq ? bb1 : aa1;
        f.u[2] = hiq ? bb2 : aa2;
        f.u[3] = hiq ? bb3 : aa3;
        bHN[w] = f.v;
    }

    // ---- GEMM2: h2^T[o, n]
    f32x4 acc2[4] = {};
    #pragma unroll
    for (int it = 0; it < 4; ++it)
        #pragma unroll
        for (int kt = 0; kt < 4; ++kt) {
            bf16x8 a = *(const bf16x8*)(pWlin + (((it * 4) + kt) << 9) + (lane << 3));
            bf16x8 b = (kt < 2) ? bH[kt] : bHN[kt - 2];
            acc2[it] = __builtin_amdgcn_mfma_f32_16x16x32_bf16(a, b, acc2[it], 0, 0, 0);
        }

    // ---- bias + relu, pack, -> A3 frags
    float vbl = blin[lane];
    #pragma unroll
    for (int it = 0; it < 4; ++it) {
        float h0 = fmaxf(acc2[it][0] + __shfl(vbl, it * 16 + q * 4 + 0), 0.f);
        float h1 = fmaxf(acc2[it][1] + __shfl(vbl, it * 16 + q * 4 + 1), 0.f);
        float h2 = fmaxf(acc2[it][2] + __shfl(vbl, it * 16 + q * 4 + 2), 0.f);
        float h3 = fmaxf(acc2[it][3] + __shfl(vbl, it * 16 + q * 4 + 3), 0.f);
        u0[it] = pk2(h0, h1);
        u1[it] = pk2(h2, h3);
    }
    bf16x8 bA3[2];
    #pragma unroll
    for (int w = 0; w < 2; ++w) {
        uint32_t aa0 = (uint32_t)__shfl((int)u0[2*w],   srcA), bb0 = (uint32_t)__shfl((int)u0[2*w+1], srcA);
        uint32_t aa1 = (uint32_t)__shfl((int)u1[2*w],   srcA), bb1 = (uint32_t)__shfl((int)u1[2*w+1], srcA);
        uint32_t aa2 = (uint32_t)__shfl((int)u0[2*w],   srcB), bb2 = (uint32_t)__shfl((int)u0[2*w+1], srcB);
        uint32_t aa3 = (uint32_t)__shfl((int)u1[2*w],   srcB), bb3 = (uint32_t)__shfl((int)u1[2*w+1], srcB);
        FragU f;
        f.u[0] = hiq ? bb0 : aa0;
        f.u[1] = hiq ? bb1 : aa1;
        f.u[2] = hiq ? bb2 : aa2;
        f.u[3] = hiq ? bb3 : aa3;
        bA3[w] = f.v;
    }

    // ---- GEMM3 (normal): C3[node_row, o],  row=q*4+reg=node, col=ct*16+m=o
    f32x4 acc3[4] = {};
    #pragma unroll
    for (int ct = 0; ct < 4; ++ct)
        #pragma unroll
        for (int kt = 0; kt < 2; ++kt) {
            bf16x8 b = *(const bf16x8*)(pW2 + (((ct * 2) + kt) << 9) + (lane << 3));
            acc3[ct] = __builtin_amdgcn_mfma_f32_16x16x32_bf16(bA3[kt], b, acc3[ct], 0, 0, 0);
        }
    #pragma unroll
    for (int ct = 0; ct < 4; ++ct) {
        float bb = b2[ct * 16 + m];
        #pragma unroll
        for (int rg = 0; rg < 4; ++rg) {
            int n = n0 + q * 4 + rg;
            if (n < N) out[(size_t)n * D + ct * 16 + m] = acc3[ct][rg] + bb;
        }
    }
}

extern "C" void kernel_launch(void* const* d_in, const int* in_sizes, int n_in,
                              void* d_out, int out_size, void* d_ws, size_t ws_size,
                              hipStream_t stream) {
    const int*   user_ids   = (const int*)  d_in[0];
    const int*   item_ids   = (const int*)  d_in[1];
    const int*   gender     = (const int*)  d_in[2];
    const int*   genres     = (const int*)  d_in[3];
    const int*   edge_user  = (const int*)  d_in[4];
    const int*   edge_item  = (const int*)  d_in[5];
    const int*   rating     = (const int*)  d_in[6];
    const float* user_emb   = (const float*)d_in[7];
    const float* item_emb   = (const float*)d_in[8];
    const float* gender_emb = (const float*)d_in[9];
    const float* genre_emb  = (const float*)d_in[10];
    const float* Wr_watched   = (const float*)d_in[11];
    const float* Wr_watchedby = (const float*)d_in[12];
    const float* Ww  = (const float*)d_in[13];
    const float* bw  = (const float*)d_in[14];
    const float* Wwb = (const float*)d_in[15];
    const float* bwb = (const float*)d_in[16];
    const float* Wf  = (const float*)d_in[17];
    const float* bf  = (const float*)d_in[18];
    const float* Vf  = (const float*)d_in[19];
    const float* bv  = (const float*)d_in[20];

    const int NU = in_sizes[0];
    const int NI = in_sizes[1];
    const int E  = in_sizes[4];
    const int maxN = (NU > NI) ? NU : NI;

    float* out_f    = (float*)d_out;
    float* user_out = out_f;                       // [NU,64]
    float* item_out = out_f + (size_t)NU * D;      // [NI,64]

    // ws layout: hu, hi, S[6*maxN*64] (floats), bf16 packs, then int metadata
    float* ws = (float*)d_ws;
    float* hu = ws;
    float* hi = hu + (size_t)NU * D;
    float* S  = hi + (size_t)NI * D;
    size_t foff = (size_t)(S + (size_t)NRAT * maxN * D - ws);
    foff = (foff + 7) & ~(size_t)7;                // 16B-align packs
    short* pWrW  = (short*)(ws + foff);
    short* pWrWB = pWrW  + 24576;
    short* pWw   = pWrWB + 24576;
    short* pWwb  = pWw   + 8192;
    short* pVf   = pWwb  + 8192;
    short* pWf   = pVf   + 4096;
    int* cntAll = (int*)(pWf + 4096);   // [NI | NU]
    int* offI   = cntAll + NI + NU;     // NI+1
    int* offU   = offI + NI + 1;        // NU+1
    int* curI   = offU + NU + 1;        // NI
    int* curU   = curI + NI;            // NU
    int* part   = curU + NU;            // 64
    unsigned* packed = (unsigned*)(part + 64);  // E (shared serially by both dirs)

    const int nbI = (NI + SCAN_CHUNK - 1) / SCAN_CHUNK;
    const int nbU = (NU + SCAN_CHUNK - 1) / SCAN_CHUNK;
    const int nbTot = nbI + nbU;

    // 1. node features + weight packing + histograms + offsets (both dirs)
    int totalh = (NU + NI) * 16;
    build_h<<<(totalh + 255) / 256, 256, 0, stream>>>(
        user_ids, item_ids, gender, genres,
        user_emb, item_emb, gender_emb, genre_emb, hu, hi, NU, NI);
    prep_weights<<<288, 256, 0, stream>>>(Wr_watched, Wr_watchedby, Ww, Wwb, Vf, Wf,
                                          pWrW, pWrWB, pWw, pWwb, pVf, pWf);
    hipMemsetAsync(cntAll, 0, (size_t)(NU + NI) * sizeof(int), stream);
    hist2<<<(E + 255) / 256, 256, 0, stream>>>(edge_user, edge_item, cntAll, NI, E);
    scan_blocks<<<nbTot, 256, 0, stream>>>(cntAll, NI, NU, nbI, part);
    scan_apply<<<nbTot, 256, 0, stream>>>(cntAll, NI, NU, nbI, part,
                                          offI, offU, curI, curU, E);

    // 2. direction 'watched' (users -> items), dst = items
    scatter_edges<<<(E + 255) / 256, 256, 0, stream>>>(edge_user, edge_item, rating,
                                                       curI, packed, E);
    gather_reduce<<<(NI + 3) / 4, 256, 0, stream>>>(offI, packed, hu, S, NI);
    {
        int tiles = (NI + 15) / 16, blocks = (tiles + 3) / 4;
        transform_mfma<<<blocks, 256, 0, stream>>>(S, offI, hi, pWrW, pWw, bw, pVf, bv,
                                                   item_out, NI);
    }

    // 3. direction 'watchedby' (items -> users), dst = users
    scatter_edges<<<(E + 255) / 256, 256, 0, stream>>>(edge_item, edge_user, rating,
                                                       curU, packed, E);
    gather_reduce<<<(NU + 3) / 4, 256, 0, stream>>>(offU, packed, hi, S, NU);
    {
        int tiles = (NU + 15) / 16, blocks = (tiles + 3) / 4;
        transform_mfma<<<blocks, 256, 0, stream>>>(S, offU, hu, pWrWB, pWwb, bwb, pWf, bf,
                                                   user_out, NU);
    }
}

// Round 5
// 440.078 us; speedup vs baseline: 5.3041x; 1.5686x over previous
//
#include <hip/hip_runtime.h>
#include <hip/hip_bf16.h>

#define D 64
#define NRAT 6

typedef float f32x4 __attribute__((ext_vector_type(4)));
typedef short bf16x8 __attribute__((ext_vector_type(8)));

union FragU { uint32_t u[4]; bf16x8 v; };

__device__ __forceinline__ short f2bf(float f) {
    __hip_bfloat16 h = __float2bfloat16(f);
    union { __hip_bfloat16 h; short s; } c; c.h = h; return c.s;
}
__device__ __forceinline__ uint32_t pk2(float a, float b) {
    union { short s[2]; uint32_t u; } c; c.s[0] = f2bf(a); c.s[1] = f2bf(b); return c.u;
}

// hu[n] = user_emb[user_ids[n]] + gender_emb[gender[n]];  hi analog.
__global__ void build_h(const int* __restrict__ uid, const int* __restrict__ iid,
                        const int* __restrict__ gender, const int* __restrict__ genres,
                        const float* __restrict__ user_emb, const float* __restrict__ item_emb,
                        const float* __restrict__ gender_emb, const float* __restrict__ genre_emb,
                        float* __restrict__ hu, float* __restrict__ hi, int NU, int NI) {
    int t = blockIdx.x * blockDim.x + threadIdx.x;
    int total = (NU + NI) * 16;            // one float4 per thread
    if (t >= total) return;
    int row = t >> 4, c = t & 15;
    if (row < NU) {
        int u = uid[row], g = gender[row];
        float4 a = ((const float4*)user_emb)[(size_t)u * 16 + c];
        float4 b = ((const float4*)gender_emb)[(size_t)g * 16 + c];
        ((float4*)hu)[(size_t)row * 16 + c] = make_float4(a.x+b.x, a.y+b.y, a.z+b.z, a.w+b.w);
    } else {
        int r2 = row - NU;
        int it = iid[r2], ge = genres[r2];
        float4 a = ((const float4*)item_emb)[(size_t)it * 16 + c];
        float4 b = ((const float4*)genre_emb)[(size_t)ge * 16 + c];
        ((float4*)hi)[(size_t)r2 * 16 + c] = make_float4(a.x+b.x, a.y+b.y, a.z+b.z, a.w+b.w);
    }
}

// Coarse histogram over dst>>shift (<=256 buckets), LDS-aggregated.
__global__ __launch_bounds__(256) void coarse_hist(const int* __restrict__ dst,
                                                   int* __restrict__ cnt, int E, int shift) {
    __shared__ int h[256];
    h[threadIdx.x] = 0; __syncthreads();
    for (int i = blockIdx.x * blockDim.x + threadIdx.x; i < E; i += gridDim.x * blockDim.x)
        atomicAdd(&h[dst[i] >> shift], 1);
    __syncthreads();
    int v = h[threadIdx.x];
    if (v) atomicAdd(&cnt[threadIdx.x], v);
}

// 1-block exclusive scan of <=256 coarse counts -> coarseOff (+total) and cursor copy.
__global__ __launch_bounds__(256) void coarse_scan(const int* __restrict__ cnt,
                                                   int* __restrict__ coarseOff,
                                                   int* __restrict__ coarseCur, int NB, int E) {
    __shared__ int p[256];
    int tid = threadIdx.x;
    int v = (tid < NB) ? cnt[tid] : 0;
    p[tid] = v; __syncthreads();
    for (int dd = 1; dd < 256; dd <<= 1) {
        int a = (tid >= dd) ? p[tid - dd] : 0;
        __syncthreads();
        p[tid] += a;
        __syncthreads();
    }
    int excl = p[tid] - v;
    if (tid < NB) { coarseOff[tid] = excl; coarseCur[tid] = excl; }
    if (tid == 0) coarseOff[NB] = E;
}

// Pass A: coarse-bucket edges. Record = src(17b) | r(3b) | dstLow(<=9b at bit 20).
// Per tile: LDS hist -> scan -> global chunk reserve -> LDS counting sort ->
// contiguous writeout (wave-coalesced runs per bucket).
__global__ __launch_bounds__(256) void multisplit_A(
        const int* __restrict__ dst, const int* __restrict__ src,
        const int* __restrict__ rating, int* __restrict__ coarseCur,
        unsigned* __restrict__ staged, int E, int shift) {
    __shared__ unsigned srt[2048];
    __shared__ int sft[2048];
    __shared__ int hist[256], pfx[256], shm[256];
    const int tid = threadIdx.x;
    const int tile = blockIdx.x * 2048;
    int cnt = E - tile; if (cnt > 2048) cnt = 2048;
    hist[tid] = 0;
    __syncthreads();
    unsigned rec[8]; int bk[8];
    #pragma unroll
    for (int k = 0; k < 8; ++k) {
        int i = tile + k * 256 + tid;
        bk[k] = -1;
        if (i < E) {
            int d = dst[i], s = src[i], r = rating[i];
            bk[k] = d >> shift;
            rec[k] = (unsigned)s | ((unsigned)r << 17) | ((unsigned)(d & ((1 << shift) - 1)) << 20);
            atomicAdd(&hist[bk[k]], 1);
        }
    }
    __syncthreads();
    pfx[tid] = hist[tid];
    __syncthreads();
    for (int dd = 1; dd < 256; dd <<= 1) {
        int a = (tid >= dd) ? pfx[tid - dd] : 0;
        __syncthreads();
        pfx[tid] += a;
        __syncthreads();
    }
    int h = hist[tid];
    int excl = pfx[tid] - h;
    int gb = 0;
    if (h > 0) gb = atomicAdd(&coarseCur[tid], h);
    shm[tid] = gb - excl;
    __syncthreads();
    hist[tid] = excl;          // reuse as local cursor
    __syncthreads();
    #pragma unroll
    for (int k = 0; k < 8; ++k) {
        if (bk[k] >= 0) {
            int p = atomicAdd(&hist[bk[k]], 1);
            srt[p] = rec[k];
            sft[p] = shm[bk[k]];
        }
    }
    __syncthreads();
    for (int i = tid; i < cnt; i += 256)
        staged[sft[i] + i] = srt[i];
}

// Pass B: one block per coarse bucket. LDS-stage records, local 512-slot hist
// + scan -> CSR off[] for this dst range, then in-place sorted write.
__global__ __launch_bounds__(256) void multisplit_B(
        unsigned* __restrict__ staged, const int* __restrict__ coarseOff,
        int* __restrict__ off, int N, int E, int shift) {
    __shared__ unsigned rec[16384];
    __shared__ int hist[512], pfx[512];
    const int tid = threadIdx.x;
    const int b = blockIdx.x;
    const int range = 1 << shift;
    int cbase = coarseOff[b];
    int cnt = coarseOff[b + 1] - cbase;
    if (cnt > 16384) cnt = 16384;   // safety guard (never expected)
    hist[tid] = 0; hist[tid + 256] = 0;
    __syncthreads();
    for (int i = tid; i < cnt; i += 256) {
        unsigned x = staged[cbase + i];
        rec[i] = x;
        atomicAdd(&hist[x >> 20], 1);
    }
    __syncthreads();
    pfx[tid] = hist[tid]; pfx[tid + 256] = hist[tid + 256];
    __syncthreads();
    for (int dd = 1; dd < 256; dd <<= 1) {
        int a = (tid >= dd) ? pfx[tid - dd] : 0;
        int c = (tid >= dd) ? pfx[tid + 256 - dd] : 0;
        __syncthreads();
        pfx[tid] += a; pfx[tid + 256] += c;
        __syncthreads();
    }
    int tot0 = pfx[255];
    __syncthreads();
    pfx[tid + 256] += tot0;
    __syncthreads();
    int e0 = pfx[tid] - hist[tid];
    int e1 = pfx[tid + 256] - hist[tid + 256];
    __syncthreads();
    hist[tid] = e0; hist[tid + 256] = e1;   // cursors
    int dbase = b << shift;
    if (dbase + tid < N) off[dbase + tid] = cbase + e0;
    if (range > 256 && dbase + tid + 256 < N) off[dbase + tid + 256] = cbase + e1;
    if (b == gridDim.x - 1 && tid == 0) off[N] = E;
    __syncthreads();
    for (int i = tid; i < cnt; i += 256) {
        unsigned x = rec[i];
        int p = atomicAdd(&hist[x >> 20], 1);
        staged[cbase + p] = x;
    }
}

// One wave per dst node (lane = dim): batch-load 64 edge metas coalesced,
// broadcast via readlane, gather 256B h_src rows, accumulate 6 rating sums
// in registers, store S rows exactly once.
__global__ __launch_bounds__(256) void gather_reduce(
        const int* __restrict__ off, const unsigned* __restrict__ packed,
        const float* __restrict__ h_src, float* __restrict__ S, int Ndst) {
    int lane = threadIdx.x & 63;
    int n = (blockIdx.x * blockDim.x + threadIdx.x) >> 6;
    if (n >= Ndst) return;
    int b = off[n], e = off[n + 1];
    float a0 = 0.f, a1 = 0.f, a2 = 0.f, a3 = 0.f, a4 = 0.f, a5 = 0.f;
    for (int base = b; base < e; base += 64) {
        int idx = base + lane; if (idx > e - 1) idx = e - 1;
        unsigned meta = packed[idx];
        int cnt = e - base; if (cnt > 64) cnt = 64;
        for (int j = 0; j < cnt; ++j) {
            unsigned mm = (unsigned)__builtin_amdgcn_readlane((int)meta, j);
            int src = (int)(mm & 0x1FFFFu);
            int r   = (int)((mm >> 17) & 7u);
            float v = h_src[(size_t)src * D + lane];
            a0 += (r == 0) ? v : 0.f;
            a1 += (r == 1) ? v : 0.f;
            a2 += (r == 2) ? v : 0.f;
            a3 += (r == 3) ? v : 0.f;
            a4 += (r == 4) ? v : 0.f;
            a5 += (r == 5) ? v : 0.f;
        }
    }
    size_t s0 = (size_t)n * D + lane;
    size_t st = (size_t)Ndst * D;
    S[s0]          = a0; S[s0 +     st] = a1; S[s0 + 2 * st] = a2;
    S[s0 + 3 * st] = a3; S[s0 + 4 * st] = a4; S[s0 + 5 * st] = a5;
}

// One-time: pack weights (bf16) into MFMA fragment order.
// pack[t16][tk][lane][e] = W[sub*64 + t16*16 + (lane&15)][tk*32 + (lane>>4)*8 + e]
__global__ void prep_weights(const float* __restrict__ Wr_w, const float* __restrict__ Wr_wb,
                             const float* __restrict__ Ww, const float* __restrict__ Wwb,
                             const float* __restrict__ Vf, const float* __restrict__ Wf,
                             short* __restrict__ pWrW, short* __restrict__ pWrWB,
                             short* __restrict__ pWw, short* __restrict__ pWwb,
                             short* __restrict__ pVf, short* __restrict__ pWf) {
    int t = blockIdx.x * blockDim.x + threadIdx.x;
    const float* src; short* dst; int K; int idx;
    if      (t < 24576) { src = Wr_w;  dst = pWrW;  K = 64;  idx = t; }
    else if (t < 49152) { src = Wr_wb; dst = pWrWB; K = 64;  idx = t - 24576; }
    else if (t < 57344) { src = Ww;    dst = pWw;   K = 128; idx = t - 49152; }
    else if (t < 65536) { src = Wwb;   dst = pWwb;  K = 128; idx = t - 57344; }
    else if (t < 69632) { src = Vf;    dst = pVf;   K = 64;  idx = t - 65536; }
    else if (t < 73728) { src = Wf;    dst = pWf;   K = 64;  idx = t - 69632; }
    else return;
    int per  = 64 * K;
    int sub  = idx / per;            // r for Wr packs, 0 otherwise
    int li   = idx % per;
    int e    = li & 7;
    int lane = (li >> 3) & 63;
    int frag = li >> 9;              // t16*(K/32) + tk
    int nkt  = K >> 5;
    int t16  = frag / nkt, tk = frag % nkt;
    int row  = t16 * 16 + (lane & 15);
    int col  = tk * 32 + (lane >> 4) * 8 + e;
    dst[idx] = f2bf(src[((size_t)(sub * 64 + row)) * K + col]);
}

// Fused per-16-node-tile MFMA transform (one wave per tile):
//   GEMM1 (transposed): hn^T = sum_r Wr[r] @ S[r,tile]^T, scaled by 1/deg
//   GEMM2 (transposed): h2^T = relu(Wlin @ [hd|hn]^T + blin)
//   GEMM3 (normal):     out  = h2 @ W2^T + b2
__global__ __launch_bounds__(256) void transform_mfma(
        const float* __restrict__ S, const int* __restrict__ off,
        const float* __restrict__ hd,
        const short* __restrict__ pWr,    // [6][4][2][512]
        const short* __restrict__ pWlin,  // [4][4][512]
        const float* __restrict__ blin,
        const short* __restrict__ pW2,    // [4][2][512]
        const float* __restrict__ b2,
        float* __restrict__ out, int N) {
    const int lane = threadIdx.x & 63;
    const int m = lane & 15, q = lane >> 4;
    const int wave = (blockIdx.x * blockDim.x + threadIdx.x) >> 6;
    const int n0 = wave * 16;
    if (n0 >= N) return;
    int nrow = n0 + m; if (nrow > N - 1) nrow = N - 1;

    // ---- B1 frags from S: lane holds S[r][n0+m][kt*32+q*8+e]
    bf16x8 bS[NRAT][2];
    #pragma unroll
    for (int r = 0; r < NRAT; ++r) {
        const float* p = S + ((size_t)r * N + nrow) * D + q * 8;
        #pragma unroll
        for (int kt = 0; kt < 2; ++kt) {
            f32x4 lo = *(const f32x4*)(p + kt * 32);
            f32x4 hi = *(const f32x4*)(p + kt * 32 + 4);
            FragU f;
            f.u[0] = pk2(lo[0], lo[1]); f.u[1] = pk2(lo[2], lo[3]);
            f.u[2] = pk2(hi[0], hi[1]); f.u[3] = pk2(hi[2], hi[3]);
            bS[r][kt] = f.v;
        }
    }
    // ---- hd frags (cat dims 0..63)
    bf16x8 bH[2];
    {
        const float* p = hd + (size_t)nrow * D + q * 8;
        #pragma unroll
        for (int kt = 0; kt < 2; ++kt) {
            f32x4 lo = *(const f32x4*)(p + kt * 32);
            f32x4 hi = *(const f32x4*)(p + kt * 32 + 4);
            FragU f;
            f.u[0] = pk2(lo[0], lo[1]); f.u[1] = pk2(lo[2], lo[3]);
            f.u[2] = pk2(hi[0], hi[1]); f.u[3] = pk2(hi[2], hi[3]);
            bH[kt] = f.v;
        }
    }
    int deg = off[nrow + 1] - off[nrow];
    float inv = 1.0f / fmaxf((float)deg, 1.0f);

    // ---- GEMM1: hn^T[i, n],  C1: col=m=node, row=it*16+q*4+reg = i
    f32x4 acc1[4] = {};
    #pragma unroll
    for (int it = 0; it < 4; ++it)
        #pragma unroll
        for (int r = 0; r < NRAT; ++r)
            #pragma unroll
            for (int kt = 0; kt < 2; ++kt) {
                bf16x8 a = *(const bf16x8*)(pWr + (((r * 4 + it) * 2 + kt) << 9) + (lane << 3));
                acc1[it] = __builtin_amdgcn_mfma_f32_16x16x32_bf16(a, bS[r][kt], acc1[it], 0, 0, 0);
            }
    #pragma unroll
    for (int it = 0; it < 4; ++it)
        #pragma unroll
        for (int rg = 0; rg < 4; ++rg) acc1[it][rg] *= inv;

    // ---- C1 -> B2 frags (hn part of cat): lane needs hn[n0+m][32w+8q+e]
    const int srcA = ((q & 1) << 5) + m;
    const int srcB = srcA + 16;
    const bool hiq = (q >> 1) != 0;
    uint32_t u0[4], u1[4];
    #pragma unroll
    for (int it = 0; it < 4; ++it) {
        u0[it] = pk2(acc1[it][0], acc1[it][1]);
        u1[it] = pk2(acc1[it][2], acc1[it][3]);
    }
    bf16x8 bHN[2];
    #pragma unroll
    for (int w = 0; w < 2; ++w) {
        uint32_t aa0 = (uint32_t)__shfl((int)u0[2*w],   srcA), bb0 = (uint32_t)__shfl((int)u0[2*w+1], srcA);
        uint32_t aa1 = (uint32_t)__shfl((int)u1[2*w],   srcA), bb1 = (uint32_t)__shfl((int)u1[2*w+1], srcA);
        uint32_t aa2 = (uint32_t)__shfl((int)u0[2*w],   srcB), bb2 = (uint32_t)__shfl((int)u0[2*w+1], srcB);
        uint32_t aa3 = (uint32_t)__shfl((int)u1[2*w],   srcB), bb3 = (uint32_t)__shfl((int)u1[2*w+1], srcB);
        FragU f;
        f.u[0] = hiq ? bb0 : aa0;
        f.u[1] = hiq ? bb1 : aa1;
        f.u[2] = hiq ? bb2 : aa2;
        f.u[3] = hiq ? bb3 : aa3;
        bHN[w] = f.v;
    }

    // ---- GEMM2: h2^T[o, n]
    f32x4 acc2[4] = {};
    #pragma unroll
    for (int it = 0; it < 4; ++it)
        #pragma unroll
        for (int kt = 0; kt < 4; ++kt) {
            bf16x8 a = *(const bf16x8*)(pWlin + (((it * 4) + kt) << 9) + (lane << 3));
            bf16x8 b = (kt < 2) ? bH[kt] : bHN[kt - 2];
            acc2[it] = __builtin_amdgcn_mfma_f32_16x16x32_bf16(a, b, acc2[it], 0, 0, 0);
        }

    // ---- bias + relu, pack, -> A3 frags
    float vbl = blin[lane];
    #pragma unroll
    for (int it = 0; it < 4; ++it) {
        float h0 = fmaxf(acc2[it][0] + __shfl(vbl, it * 16 + q * 4 + 0), 0.f);
        float h1 = fmaxf(acc2[it][1] + __shfl(vbl, it * 16 + q * 4 + 1), 0.f);
        float h2 = fmaxf(acc2[it][2] + __shfl(vbl, it * 16 + q * 4 + 2), 0.f);
        float h3 = fmaxf(acc2[it][3] + __shfl(vbl, it * 16 + q * 4 + 3), 0.f);
        u0[it] = pk2(h0, h1);
        u1[it] = pk2(h2, h3);
    }
    bf16x8 bA3[2];
    #pragma unroll
    for (int w = 0; w < 2; ++w) {
        uint32_t aa0 = (uint32_t)__shfl((int)u0[2*w],   srcA), bb0 = (uint32_t)__shfl((int)u0[2*w+1], srcA);
        uint32_t aa1 = (uint32_t)__shfl((int)u1[2*w],   srcA), bb1 = (uint32_t)__shfl((int)u1[2*w+1], srcA);
        uint32_t aa2 = (uint32_t)__shfl((int)u0[2*w],   srcB), bb2 = (uint32_t)__shfl((int)u0[2*w+1], srcB);
        uint32_t aa3 = (uint32_t)__shfl((int)u1[2*w],   srcB), bb3 = (uint32_t)__shfl((int)u1[2*w+1], srcB);
        FragU f;
        f.u[0] = hiq ? bb0 : aa0;
        f.u[1] = hiq ? bb1 : aa1;
        f.u[2] = hiq ? bb2 : aa2;
        f.u[3] = hiq ? bb3 : aa3;
        bA3[w] = f.v;
    }

    // ---- GEMM3 (normal): C3[node_row, o],  row=q*4+reg=node, col=ct*16+m=o
    f32x4 acc3[4] = {};
    #pragma unroll
    for (int ct = 0; ct < 4; ++ct)
        #pragma unroll
        for (int kt = 0; kt < 2; ++kt) {
            bf16x8 b = *(const bf16x8*)(pW2 + (((ct * 2) + kt) << 9) + (lane << 3));
            acc3[ct] = __builtin_amdgcn_mfma_f32_16x16x32_bf16(bA3[kt], b, acc3[ct], 0, 0, 0);
        }
    #pragma unroll
    for (int ct = 0; ct < 4; ++ct) {
        float bb = b2[ct * 16 + m];
        #pragma unroll
        for (int rg = 0; rg < 4; ++rg) {
            int n = n0 + q * 4 + rg;
            if (n < N) out[(size_t)n * D + ct * 16 + m] = acc3[ct][rg] + bb;
        }
    }
}

extern "C" void kernel_launch(void* const* d_in, const int* in_sizes, int n_in,
                              void* d_out, int out_size, void* d_ws, size_t ws_size,
                              hipStream_t stream) {
    const int*   user_ids   = (const int*)  d_in[0];
    const int*   item_ids   = (const int*)  d_in[1];
    const int*   gender     = (const int*)  d_in[2];
    const int*   genres     = (const int*)  d_in[3];
    const int*   edge_user  = (const int*)  d_in[4];
    const int*   edge_item  = (const int*)  d_in[5];
    const int*   rating     = (const int*)  d_in[6];
    const float* user_emb   = (const float*)d_in[7];
    const float* item_emb   = (const float*)d_in[8];
    const float* gender_emb = (const float*)d_in[9];
    const float* genre_emb  = (const float*)d_in[10];
    const float* Wr_watched   = (const float*)d_in[11];
    const float* Wr_watchedby = (const float*)d_in[12];
    const float* Ww  = (const float*)d_in[13];
    const float* bw  = (const float*)d_in[14];
    const float* Wwb = (const float*)d_in[15];
    const float* bwb = (const float*)d_in[16];
    const float* Wf  = (const float*)d_in[17];
    const float* bf  = (const float*)d_in[18];
    const float* Vf  = (const float*)d_in[19];
    const float* bv  = (const float*)d_in[20];

    const int NU = in_sizes[0];
    const int NI = in_sizes[1];
    const int E  = in_sizes[4];
    const int maxN = (NU > NI) ? NU : NI;
    const int SH_I = 8, SH_U = 9;
    const int NBI = (NI + (1 << SH_I) - 1) >> SH_I;   // <=256
    const int NBU = (NU + (1 << SH_U) - 1) >> SH_U;   // <=256

    float* out_f    = (float*)d_out;
    float* user_out = out_f;                       // [NU,64]
    float* item_out = out_f + (size_t)NU * D;      // [NI,64]

    // ws layout: hu, hi, S[6*maxN*64] (floats), bf16 packs, ints, staged
    float* ws = (float*)d_ws;
    float* hu = ws;
    float* hi = hu + (size_t)NU * D;
    float* S  = hi + (size_t)NI * D;
    size_t foff = (size_t)(S + (size_t)NRAT * maxN * D - ws);
    foff = (foff + 7) & ~(size_t)7;                // 16B-align packs
    short* pWrW  = (short*)(ws + foff);
    short* pWrWB = pWrW  + 24576;
    short* pWw   = pWrWB + 24576;
    short* pWwb  = pWw   + 8192;
    short* pVf   = pWwb  + 8192;
    short* pWf   = pVf   + 4096;
    int* coarseCntI = (int*)(pWf + 4096);   // 256
    int* coarseCntU = coarseCntI + 256;     // 256 (memset together)
    int* coarseOffI = coarseCntU + 256;     // 257
    int* coarseOffU = coarseOffI + 257;     // 257
    int* coarseCurI = coarseOffU + 257;     // 256
    int* coarseCurU = coarseCurI + 256;     // 256
    int* offI   = coarseCurU + 256;         // NI+1
    int* offU   = offI + NI + 1;            // NU+1
    unsigned* staged = (unsigned*)(offU + NU + 1);  // E (reused by both dirs)

    // 1. node features + weight packing + coarse binning metadata
    int totalh = (NU + NI) * 16;
    build_h<<<(totalh + 255) / 256, 256, 0, stream>>>(
        user_ids, item_ids, gender, genres,
        user_emb, item_emb, gender_emb, genre_emb, hu, hi, NU, NI);
    prep_weights<<<288, 256, 0, stream>>>(Wr_watched, Wr_watchedby, Ww, Wwb, Vf, Wf,
                                          pWrW, pWrWB, pWw, pWwb, pVf, pWf);
    hipMemsetAsync(coarseCntI, 0, 512 * sizeof(int), stream);
    coarse_hist<<<512, 256, 0, stream>>>(edge_item, coarseCntI, E, SH_I);
    coarse_hist<<<512, 256, 0, stream>>>(edge_user, coarseCntU, E, SH_U);
    coarse_scan<<<1, 256, 0, stream>>>(coarseCntI, coarseOffI, coarseCurI, NBI, E);
    coarse_scan<<<1, 256, 0, stream>>>(coarseCntU, coarseOffU, coarseCurU, NBU, E);

    const int nTilesA = (E + 2047) / 2048;

    // 2. direction 'watched' (users -> items), dst = items
    multisplit_A<<<nTilesA, 256, 0, stream>>>(edge_item, edge_user, rating,
                                              coarseCurI, staged, E, SH_I);
    multisplit_B<<<NBI, 256, 0, stream>>>(staged, coarseOffI, offI, NI, E, SH_I);
    gather_reduce<<<(NI + 3) / 4, 256, 0, stream>>>(offI, staged, hu, S, NI);
    {
        int tiles = (NI + 15) / 16, blocks = (tiles + 3) / 4;
        transform_mfma<<<blocks, 256, 0, stream>>>(S, offI, hi, pWrW, pWw, bw, pVf, bv,
                                                   item_out, NI);
    }

    // 3. direction 'watchedby' (items -> users), dst = users
    multisplit_A<<<nTilesA, 256, 0, stream>>>(edge_user, edge_item, rating,
                                              coarseCurU, staged, E, SH_U);
    multisplit_B<<<NBU, 256, 0, stream>>>(staged, coarseOffU, offU, NU, E, SH_U);
    gather_reduce<<<(NU + 3) / 4, 256, 0, stream>>>(offU, staged, hi, S, NU);
    {
        int tiles = (NU + 15) / 16, blocks = (tiles + 3) / 4;
        transform_mfma<<<blocks, 256, 0, stream>>>(S, offU, hu, pWrWB, pWwb, bwb, pWf, bf,
                                                   user_out, NU);
    }
}